// Round 2
// baseline (109.323 us; speedup 1.0000x reference)
//
#include <hip/hip_runtime.h>

#define BINS 10

// Per-element: idx = min(int(g*10),9) replicates searchsorted(right)-1 except
// within ~1ulp of an edge (negligible: weight shift ~1e-6 on a 0.93 loss,
// threshold 1.86e-2). Counts packed 6 bits/bin in a u64 (flushed every <=60
// elems). BCE scattered to a per-wave LDS float histogram via ds_add_f32.
__device__ __forceinline__ void ghm_elem(float x, float tt,
                                         unsigned long long& pk,
                                         float* __restrict__ whist) {
    float t = __expf(-fabsf(x));                 // e^{-|x|}  (mul+v_exp)
    float u = 1.f + t;
    float r = __builtin_amdgcn_rcpf(u);          // ~1ulp approx, ample slack
    float sig = (x >= 0.f) ? r : t * r;          // sigmoid(x), all ranges
    float d = sig - tt;
    int idx = (int)(fabsf(d) * 10.f);            // trunc
    idx = idx < 9 ? idx : 9;
    pk += 1ull << (6 * idx);                     // packed count
    float bce = fmaxf(x, 0.f) - x * tt + __logf(u);  // log1p(e^{-|x|}) = log(u)
    atomicAdd(&whist[idx], bce);                 // ds_add_f32, wave-private row
}

__global__ __launch_bounds__(256) void ghm_pass1(
    const float* __restrict__ pred, const float* __restrict__ tgt,
    long long n, int nb,
    float* __restrict__ bsum, int* __restrict__ bcnt)
{
    __shared__ float shist[4][BINS];   // per-wave private bce histograms
    __shared__ float rsum[4][BINS];
    __shared__ int   rcnt[4][BINS];

    const int lane = threadIdx.x & 63;
    const int wave = threadIdx.x >> 6;
    if (lane < BINS) shist[wave][lane] = 0.f;
    __syncthreads();

    float* whist = &shist[wave][0];

    unsigned long long pk = 0;
    int c[BINS];
#pragma unroll
    for (int b = 0; b < BINS; ++b) c[b] = 0;

    const long long n4 = n >> 2;
    const float4* p4 = (const float4*)pred;
    const float4* t4 = (const float4*)tgt;
    const long long stride = (long long)nb * 256;

    int chunk = 0;
    for (long long i = (long long)blockIdx.x * 256 + threadIdx.x; i < n4; i += stride) {
        float4 p = p4[i];
        float4 t = t4[i];
        ghm_elem(p.x, t.x, pk, whist);
        ghm_elem(p.y, t.y, pk, whist);
        ghm_elem(p.z, t.z, pk, whist);
        ghm_elem(p.w, t.w, pk, whist);
        if (++chunk == 15) {           // 60 elems max per flush (6-bit fields)
            chunk = 0;
#pragma unroll
            for (int b = 0; b < BINS; ++b) c[b] += (int)((pk >> (6 * b)) & 63u);
            pk = 0;
        }
    }

    // tail (n not divisible by 4): block 0, scalar — adds at most 1 elem (<=61 in pk)
    const long long tail0 = n4 << 2;
    if (blockIdx.x == 0 && (long long)threadIdx.x < (n - tail0)) {
        long long i = tail0 + threadIdx.x;
        ghm_elem(pred[i], tgt[i], pk, whist);
    }
#pragma unroll
    for (int b = 0; b < BINS; ++b) c[b] += (int)((pk >> (6 * b)) & 63u);

    __syncthreads();   // shist complete

    // reduce counts across lanes (deterministic shuffle tree)
#pragma unroll
    for (int b = 0; b < BINS; ++b) {
        int k = c[b];
        for (int off = 32; off; off >>= 1) k += __shfl_down(k, off);
        if (lane == 0) rcnt[wave][b] = k;
    }
    if (lane < BINS) rsum[wave][lane] = shist[wave][lane];
    __syncthreads();

    if (threadIdx.x < BINS) {
        int b = threadIdx.x;
        float v = rsum[0][b] + rsum[1][b] + rsum[2][b] + rsum[3][b];
        int   k = rcnt[0][b] + rcnt[1][b] + rcnt[2][b] + rcnt[3][b];
        bsum[(long long)b * nb + blockIdx.x] = v;   // bin-major for pass2
        bcnt[(long long)b * nb + blockIdx.x] = k;
    }
}

// 10 waves, one bin per wave: parallel strided loads, shuffle reduce.
__global__ __launch_bounds__(640) void ghm_pass2(
    const float* __restrict__ bsum, const int* __restrict__ bcnt,
    int nb, float* __restrict__ out)
{
    __shared__ double    ssum[BINS];
    __shared__ long long scnt[BINS];
    const int lane = threadIdx.x & 63;
    const int wave = threadIdx.x >> 6;   // 0..9 == bin

    double    acc = 0.0;
    long long cc  = 0;
    for (int i = lane; i < nb; i += 64) {
        acc += (double)bsum[(long long)wave * nb + i];
        cc  += (long long)bcnt[(long long)wave * nb + i];
    }
    for (int off = 32; off; off >>= 1) {
        acc += __shfl_down(acc, off);
        cc  += __shfl_down(cc, off);
    }
    if (lane == 0) { ssum[wave] = acc; scnt[wave] = cc; }
    __syncthreads();

    if (threadIdx.x == 0) {
        int n = 0;
#pragma unroll
        for (int b = 0; b < BINS; ++b) n += (scnt[b] > 0) ? 1 : 0;
        double loss = 0.0;
        if (n > 0) {
#pragma unroll
            for (int b = 0; b < BINS; ++b)
                if (scnt[b] > 0)
                    loss += ssum[b] / ((double)scnt[b] * (double)n);
        }
        out[0] = (float)loss;
    }
}

extern "C" void kernel_launch(void* const* d_in, const int* in_sizes, int n_in,
                              void* d_out, int out_size, void* d_ws, size_t ws_size,
                              hipStream_t stream) {
    const float* pred = (const float*)d_in[0];
    const float* tgt  = (const float*)d_in[1];
    float* out = (float*)d_out;
    const long long n = (long long)in_sizes[0];

    int nb = 2048;
    const size_t per_block = (size_t)BINS * (sizeof(float) + sizeof(int)); // 80 B
    if ((size_t)nb * per_block > ws_size) nb = (int)(ws_size / per_block);
    if (nb < 1) nb = 1;

    float* bsum = (float*)d_ws;
    int*   bcnt = (int*)((char*)d_ws + (size_t)nb * BINS * sizeof(float));

    ghm_pass1<<<nb, 256, 0, stream>>>(pred, tgt, n, nb, bsum, bcnt);
    ghm_pass2<<<1, 640, 0, stream>>>(bsum, bcnt, nb, out);
}